// Round 2
// baseline (2236.306 us; speedup 1.0000x reference)
//
#include <hip/hip_runtime.h>

#define CIN  32
#define COUT 64
#define KOFF 27
#define EPS  1e-5f

// One wave (64 lanes) per kernel-map pair: lane <-> output column.
// W[k] staged in LDS (8 KB). feats row read as 8 broadcast float4 loads.
// Scatter via coalesced 64-lane atomicAdd (contiguous 256B per wave).
__global__ __launch_bounds__(256) void conv_scatter(
    const float* __restrict__ feats,    // [N, CIN]
    const float* __restrict__ W,        // [K, CIN, COUT]
    const int*   __restrict__ in_idx,   // [K, M]
    const int*   __restrict__ out_idx,  // [K, M]
    float*       __restrict__ out,      // [N, COUT]
    int M)
{
    __shared__ float Wl[CIN * COUT];    // 8 KB
    const int k   = blockIdx.x;
    const int tid = threadIdx.x;

    const float* Wk = W + (size_t)k * (CIN * COUT);
    for (int i = tid; i < CIN * COUT; i += 256) Wl[i] = Wk[i];
    __syncthreads();

    const int lane = tid & 63;
    const int wave = tid >> 6;
    const int wavesTotal = gridDim.y * 4;
    const int* ikb = in_idx  + (size_t)k * M;
    const int* okb = out_idx + (size_t)k * M;

    for (int m = blockIdx.y * 4 + wave; m < M; m += wavesTotal) {
        const int ik = ikb[m];
        const int ok = okb[m];
        const float4* f4 = (const float4*)(feats + (size_t)ik * CIN);
        float acc = 0.f;
        #pragma unroll
        for (int c0 = 0; c0 < CIN / 4; ++c0) {
            float4 f = f4[c0];   // wave-uniform broadcast load
            acc += f.x * Wl[(c0 * 4 + 0) * COUT + lane];
            acc += f.y * Wl[(c0 * 4 + 1) * COUT + lane];
            acc += f.z * Wl[(c0 * 4 + 2) * COUT + lane];
            acc += f.w * Wl[(c0 * 4 + 3) * COUT + lane];
        }
        atomicAdd(out + (size_t)ok * COUT + lane, acc);
    }
}

// In-place BN(inference) + ReLU, float4-vectorized.
__global__ __launch_bounds__(256) void bn_relu(
    float* __restrict__ out,
    const float* __restrict__ gamma,
    const float* __restrict__ beta,
    const float* __restrict__ rmean,
    const float* __restrict__ rvar,
    int total4)                          // N*COUT/4
{
    __shared__ float scale[COUT], shift[COUT];
    if (threadIdx.x < COUT) {
        const int c = threadIdx.x;
        const float inv = rsqrtf(rvar[c] + EPS);
        const float s = inv * gamma[c];
        scale[c] = s;
        shift[c] = beta[c] - rmean[c] * s;
    }
    __syncthreads();

    const int stride = gridDim.x * blockDim.x;
    for (int i = blockIdx.x * blockDim.x + threadIdx.x; i < total4; i += stride) {
        float4 v = ((const float4*)out)[i];
        const int c0 = (i * 4) & (COUT - 1);
        v.x = fmaxf(v.x * scale[c0 + 0] + shift[c0 + 0], 0.f);
        v.y = fmaxf(v.y * scale[c0 + 1] + shift[c0 + 1], 0.f);
        v.z = fmaxf(v.z * scale[c0 + 2] + shift[c0 + 2], 0.f);
        v.w = fmaxf(v.w * scale[c0 + 3] + shift[c0 + 3], 0.f);
        ((float4*)out)[i] = v;
    }
}

extern "C" void kernel_launch(void* const* d_in, const int* in_sizes, int n_in,
                              void* d_out, int out_size, void* d_ws, size_t ws_size,
                              hipStream_t stream) {
    const float* feats  = (const float*)d_in[0];
    const float* W      = (const float*)d_in[1];
    const float* gamma  = (const float*)d_in[2];
    const float* beta   = (const float*)d_in[3];
    const float* rmean  = (const float*)d_in[4];
    const float* rvar   = (const float*)d_in[5];
    const int*   in_idx  = (const int*)d_in[6];
    const int*   out_idx = (const int*)d_in[7];
    float* out = (float*)d_out;

    const int N = in_sizes[0] / CIN;
    const int M = in_sizes[6] / KOFF;

    hipMemsetAsync(out, 0, (size_t)N * COUT * sizeof(float), stream);

    dim3 grid(KOFF, 512);   // 27 x 512 blocks; 2048 waves per offset
    conv_scatter<<<grid, 256, 0, stream>>>(feats, W, in_idx, out_idx, out, M);

    const int total4 = N * COUT / 4;
    int blocks = (total4 + 255) / 256;
    if (blocks > 2048) blocks = 2048;
    bn_relu<<<blocks, 256, 0, stream>>>(out, gamma, beta, rmean, rvar, total4);
}